// Round 1
// baseline (416.086 us; speedup 1.0000x reference)
//
#include <hip/hip_runtime.h>
#include <hip/hip_bf16.h>

// LengthRegulator (FastSpeech): expanded gather + mel_len + mel_mask.
// Outputs concatenated flat in d_out as float32:
//   [0, B*max_len*D)                      expanded
//   [B*max_len*D, +B)                     mel_len (as float)
//   [B*max_len*D + B, +B*max_len)         mel_mask (0.0 / 1.0)

#define S_TOK 1024  // tokens per sequence
#define B_SZ  32    // batch

// One block per batch: inclusive scan of durations -> csum (ws), mel_len (out).
__global__ __launch_bounds__(S_TOK)
void lr_cumsum_kernel(const int* __restrict__ dur,
                      int* __restrict__ csum,
                      float* __restrict__ mel_len_out) {
    const int b = blockIdx.x;
    const int tid = threadIdx.x;
    __shared__ int buf[S_TOK];
    buf[tid] = dur[b * S_TOK + tid];
    __syncthreads();
    // Hillis-Steele inclusive scan
    for (int off = 1; off < S_TOK; off <<= 1) {
        int add = (tid >= off) ? buf[tid - off] : 0;
        __syncthreads();
        buf[tid] += add;
        __syncthreads();
    }
    csum[b * S_TOK + tid] = buf[tid];
    if (tid == S_TOK - 1) mel_len_out[b] = (float)buf[tid];
}

// One block per output frame (t, b). 128 threads x float4 = 512 floats.
__global__ __launch_bounds__(128)
void lr_expand_kernel(const float* __restrict__ x,
                      const int* __restrict__ csum,
                      float* __restrict__ out,
                      float* __restrict__ mask,
                      int D, int max_len) {
    const int t = blockIdx.x;
    const int b = blockIdx.y;
    const int tid = threadIdx.x;
    const int* __restrict__ c = csum + b * S_TOK;
    const int mel = c[S_TOK - 1];

    float4* __restrict__ orow =
        (float4*)(out + ((size_t)b * max_len + t) * (size_t)D);

    if (t >= mel) {
        orow[tid] = make_float4(0.f, 0.f, 0.f, 0.f);
        if (tid == 0) mask[(size_t)b * max_len + t] = 1.0f;
        return;
    }

    // first j with c[j] > t  (t < mel = c[S-1], so j < S always)
    int lo = 0, hi = S_TOK;
    while (lo < hi) {
        int mid = (lo + hi) >> 1;
        if (c[mid] > t) hi = mid; else lo = mid + 1;
    }
    const int idx = lo;

    const float4* __restrict__ xrow =
        (const float4*)(x + ((size_t)b * S_TOK + idx) * (size_t)D);
    orow[tid] = xrow[tid];
    if (tid == 0) mask[(size_t)b * max_len + t] = 0.0f;
}

extern "C" void kernel_launch(void* const* d_in, const int* in_sizes, int n_in,
                              void* d_out, int out_size, void* d_ws, size_t ws_size,
                              hipStream_t stream) {
    const float* x = (const float*)d_in[0];
    const int* dur = (const int*)d_in[1];
    float* out = (float*)d_out;

    const int D = in_sizes[0] / in_sizes[1];                 // 512
    const int max_len = (out_size / B_SZ - 1) / (D + 1);     // data-dependent, from out_size

    int* csum = (int*)d_ws;                                  // B*S ints = 128 KB
    float* mel_len = out + (size_t)B_SZ * max_len * D;
    float* mask = mel_len + B_SZ;

    lr_cumsum_kernel<<<B_SZ, S_TOK, 0, stream>>>(dur, csum, mel_len);

    dim3 grid((unsigned)max_len, (unsigned)B_SZ);
    lr_expand_kernel<<<grid, 128, 0, stream>>>(x, csum, out, mask, D, max_len);
}

// Round 2
// 370.777 us; speedup vs baseline: 1.1222x; 1.1222x over previous
//
#include <hip/hip_runtime.h>
#include <hip/hip_bf16.h>

// LengthRegulator (FastSpeech): expanded gather + mel_len + mel_mask.
// Outputs concatenated flat in d_out as float32:
//   [0, B*max_len*D)                      expanded
//   [B*max_len*D, +B)                     mel_len (as float)
//   [B*max_len*D + B, +B*max_len)         mel_mask (0.0 / 1.0)
//
// R1 -> R2: frame-major gather (binary search per frame, row re-fetched
// across XCD L2s) replaced by token-major scatter: each block reads its
// 2KB row once and writes it to dur consecutive frames. Read traffic
// 311MB -> 64MB, no dependent search chain before stores.

#define S_TOK 1024  // tokens per sequence
#define B_SZ  32    // batch

// One block per batch: inclusive scan of durations -> csum (ws), mel_len (out).
__global__ __launch_bounds__(S_TOK)
void lr_cumsum_kernel(const int* __restrict__ dur,
                      int* __restrict__ csum,
                      float* __restrict__ mel_len_out) {
    const int b = blockIdx.x;
    const int tid = threadIdx.x;
    __shared__ int buf[S_TOK];
    buf[tid] = dur[b * S_TOK + tid];
    __syncthreads();
    for (int off = 1; off < S_TOK; off <<= 1) {
        int add = (tid >= off) ? buf[tid - off] : 0;
        __syncthreads();
        buf[tid] += add;
        __syncthreads();
    }
    csum[b * S_TOK + tid] = buf[tid];
    if (tid == S_TOK - 1) mel_len_out[b] = (float)buf[tid];
}

// Token-major scatter: block (s,b) copies x[b,s,:] to out frames
// [csum[s-1], csum[s]). 128 threads x float4 = 512 floats, row held in regs.
__global__ __launch_bounds__(128)
void lr_scatter_kernel(const float* __restrict__ x,
                       const int* __restrict__ csum,
                       float* __restrict__ out,
                       int D, int max_len) {
    const int s = blockIdx.x;
    const int b = blockIdx.y;
    const int tid = threadIdx.x;
    const int* __restrict__ c = csum + b * S_TOK;
    const int base = (s == 0) ? 0 : c[s - 1];
    const int end  = c[s];

    const float4 v =
        ((const float4*)(x + ((size_t)b * S_TOK + s) * (size_t)D))[tid];
    float4* __restrict__ o =
        (float4*)(out + ((size_t)b * max_len + base) * (size_t)D) + tid;
    const int d4 = D >> 2;
    for (int r = 0; r < end - base; ++r) {
        o[(size_t)r * d4] = v;
    }
}

// Zero-fill tail frames [mel_b, max_len). Blocks past the tail exit fast.
__global__ __launch_bounds__(128)
void lr_tail_kernel(const int* __restrict__ csum,
                    float* __restrict__ out,
                    int D, int max_len) {
    const int b = blockIdx.y;
    const int tid = threadIdx.x;
    const int mel = csum[b * S_TOK + S_TOK - 1];
    const int t0 = mel + blockIdx.x * 4;
    if (t0 >= max_len) return;
    const float4 z = make_float4(0.f, 0.f, 0.f, 0.f);
#pragma unroll
    for (int k = 0; k < 4; ++k) {
        const int t = t0 + k;
        if (t < max_len)
            ((float4*)(out + ((size_t)b * max_len + t) * (size_t)D))[tid] = z;
    }
}

// mask[b,t] = t >= mel_b. Grid (ceil(max_len/256), B).
__global__ __launch_bounds__(256)
void lr_mask_kernel(const int* __restrict__ csum,
                    float* __restrict__ mask,
                    int max_len) {
    const int b = blockIdx.y;
    const int t = blockIdx.x * 256 + threadIdx.x;
    if (t >= max_len) return;
    const int mel = csum[b * S_TOK + S_TOK - 1];
    mask[(size_t)b * max_len + t] = (t >= mel) ? 1.0f : 0.0f;
}

extern "C" void kernel_launch(void* const* d_in, const int* in_sizes, int n_in,
                              void* d_out, int out_size, void* d_ws, size_t ws_size,
                              hipStream_t stream) {
    const float* x = (const float*)d_in[0];
    const int* dur = (const int*)d_in[1];
    float* out = (float*)d_out;

    const int D = in_sizes[0] / in_sizes[1];                 // 512
    const int max_len = (out_size / B_SZ - 1) / (D + 1);     // data-dependent, from out_size

    int* csum = (int*)d_ws;                                  // B*S ints = 128 KB
    float* mel_len = out + (size_t)B_SZ * max_len * D;
    float* mask = mel_len + B_SZ;

    lr_cumsum_kernel<<<B_SZ, S_TOK, 0, stream>>>(dur, csum, mel_len);

    dim3 sgrid((unsigned)S_TOK, (unsigned)B_SZ);
    lr_scatter_kernel<<<sgrid, D / 4, 0, stream>>>(x, csum, out, D, max_len);

    dim3 tgrid((unsigned)((max_len + 3) / 4), (unsigned)B_SZ);
    lr_tail_kernel<<<tgrid, D / 4, 0, stream>>>(csum, out, D, max_len);

    dim3 mgrid((unsigned)((max_len + 255) / 256), (unsigned)B_SZ);
    lr_mask_kernel<<<mgrid, 256, 0, stream>>>(csum, mask, max_len);
}

// Round 4
// 353.134 us; speedup vs baseline: 1.1783x; 1.0500x over previous
//
#include <hip/hip_runtime.h>
#include <hip/hip_bf16.h>

// LengthRegulator (FastSpeech): expanded gather + mel_len + mel_mask.
// Outputs concatenated flat in d_out as float32:
//   [0, B*max_len*D)                      expanded
//   [B*max_len*D, +B)                     mel_len (as float)
//   [B*max_len*D + B, +B*max_len)         mel_mask (0.0 / 1.0)
//
// R3 -> R4: same 2-kernel design; non-temporal stores now use a native
// clang ext_vector float4 (HIP's float4 struct is rejected by
// __builtin_nontemporal_store).

#define S_TOK 1024  // tokens per sequence
#define B_SZ  32    // batch

typedef float vfloat4 __attribute__((ext_vector_type(4)));

// One wave per batch: 16 durations/lane serial prefix + wave shuffle scan.
__global__ __launch_bounds__(64)
void lr_scan_kernel(const int* __restrict__ dur,
                    int* __restrict__ csum,
                    float* __restrict__ mel_len_out) {
    const int b = blockIdx.x;
    const int lane = threadIdx.x;
    const int* __restrict__ d = dur + b * S_TOK;

    int v[16];
    int sum = 0;
#pragma unroll
    for (int k = 0; k < 16; ++k) {
        v[k] = d[lane * 16 + k];
        sum += v[k];
    }
    // inclusive within-lane prefix
    int run = 0;
#pragma unroll
    for (int k = 0; k < 16; ++k) { run += v[k]; v[k] = run; }

    // wave inclusive scan of per-lane sums
    int tot = sum;
#pragma unroll
    for (int off = 1; off < 64; off <<= 1) {
        int n = __shfl_up(tot, off, 64);
        if (lane >= off) tot += n;
    }
    const int excl = tot - sum;

#pragma unroll
    for (int k = 0; k < 16; ++k)
        csum[b * S_TOK + lane * 16 + k] = v[k] + excl;
    if (lane == 63) mel_len_out[b] = (float)tot;
}

// Fused scatter + tail-zero + mask.
// blockIdx.x in [0, S_TOK): token s scatter — copy x[b,s,:] to frames
//   [c[s-1], c[s]), write mask=0 for those frames.
// blockIdx.x in [S_TOK, S_TOK+tail): zero-fill 4 frames starting at
//   mel + 4*(blockIdx.x - S_TOK), write mask=1.
__global__ __launch_bounds__(128)
void lr_fused_kernel(const float* __restrict__ x,
                     const int* __restrict__ csum,
                     float* __restrict__ out,
                     float* __restrict__ mask,
                     int D, int max_len) {
    const int b = blockIdx.y;
    const int tid = threadIdx.x;
    const int* __restrict__ c = csum + b * S_TOK;
    const int d4 = D >> 2;

    if (blockIdx.x < S_TOK) {
        const int s = blockIdx.x;
        const int base = (s == 0) ? 0 : c[s - 1];
        const int dur = c[s] - base;

        const vfloat4 v =
            ((const vfloat4*)(x + ((size_t)b * S_TOK + s) * (size_t)D))[tid];
        vfloat4* __restrict__ o =
            (vfloat4*)(out + ((size_t)b * max_len + base) * (size_t)D) + tid;
        for (int r = 0; r < dur; ++r)
            __builtin_nontemporal_store(v, o + (size_t)r * d4);
        if (tid < dur)
            mask[(size_t)b * max_len + base + tid] = 0.0f;
    } else {
        const int mel = c[S_TOK - 1];
        const int t0 = mel + (blockIdx.x - S_TOK) * 4;
        if (t0 >= max_len) return;
        const vfloat4 z = (vfloat4)(0.f);
#pragma unroll
        for (int k = 0; k < 4; ++k) {
            const int t = t0 + k;
            if (t < max_len) {
                vfloat4* __restrict__ o =
                    (vfloat4*)(out + ((size_t)b * max_len + t) * (size_t)D) + tid;
                __builtin_nontemporal_store(z, o);
            }
        }
        if (tid < 4 && t0 + tid < max_len)
            mask[(size_t)b * max_len + t0 + tid] = 1.0f;
    }
}

extern "C" void kernel_launch(void* const* d_in, const int* in_sizes, int n_in,
                              void* d_out, int out_size, void* d_ws, size_t ws_size,
                              hipStream_t stream) {
    const float* x = (const float*)d_in[0];
    const int* dur = (const int*)d_in[1];
    float* out = (float*)d_out;

    const int D = in_sizes[0] / in_sizes[1];                 // 512
    const int max_len = (out_size / B_SZ - 1) / (D + 1);     // data-dependent, from out_size

    int* csum = (int*)d_ws;                                  // B*S ints = 128 KB
    float* mel_len = out + (size_t)B_SZ * max_len * D;
    float* mask = mel_len + B_SZ;

    lr_scan_kernel<<<B_SZ, 64, 0, stream>>>(dur, csum, mel_len);

    // tail worst case: mel >= S_TOK (dur >= 1), so at most
    // ceil((max_len - S_TOK)/4) tail blocks are ever needed; +1 slack.
    const int tail_blocks = (max_len > S_TOK) ? ((max_len - S_TOK + 3) / 4 + 1) : 1;
    dim3 fgrid((unsigned)(S_TOK + tail_blocks), (unsigned)B_SZ);
    lr_fused_kernel<<<fgrid, 128, 0, stream>>>(x, csum, out, mask, D, max_len);
}